// Round 8
// baseline (667.405 us; speedup 1.0000x reference)
//
#include <hip/hip_runtime.h>
#include <stdint.h>

typedef __attribute__((ext_vector_type(8))) __bf16 bf16x8;
typedef __attribute__((ext_vector_type(4))) float f32x4;

__device__ __forceinline__ unsigned short f2bf(float f) {
  union { float f; unsigned int u; } v; v.f = f;
  unsigned int u = v.u;
  u = (u + 0x7FFFu + ((u >> 16) & 1u)) >> 16;   // RNE
  return (unsigned short)u;
}
__device__ __forceinline__ float bf2f(unsigned int u) {
  union { unsigned int u; float f; } v; v.u = u << 16;
  return v.f;
}

// ---------------------------------------------------------------------------
// Kernel 1: transpose + bf16-convert the three DxD weight matrices:
// Wt[n][k] = (bf16) W[k][n]  (B-operand fragments read 16B contiguous in K).
// ---------------------------------------------------------------------------
__global__ __launch_bounds__(256) void wconv(
    const float* __restrict__ Wa, const float* __restrict__ Wsh,
    const float* __restrict__ Wsc,
    unsigned short* __restrict__ Oa, unsigned short* __restrict__ Osh,
    unsigned short* __restrict__ Osc)
{
  const float* W; unsigned short* O;
  if (blockIdx.z == 0)      { W = Wa;  O = Oa; }
  else if (blockIdx.z == 1) { W = Wsh; O = Osh; }
  else                      { W = Wsc; O = Osc; }
  const int k0 = blockIdx.x * 64;
  const int n0 = blockIdx.y * 64;
  __shared__ float t[64][65];
  const int r = threadIdx.x >> 4;
  const int c4 = threadIdx.x & 15;
#pragma unroll
  for (int i = 0; i < 4; ++i) {
    const int row = r + i * 16;
    const float4 v = *(const float4*)(W + (size_t)(k0 + row) * 1024 + n0 + c4 * 4);
    t[row][c4 * 4 + 0] = v.x; t[row][c4 * 4 + 1] = v.y;
    t[row][c4 * 4 + 2] = v.z; t[row][c4 * 4 + 3] = v.w;
  }
  __syncthreads();
#pragma unroll
  for (int i = 0; i < 4; ++i) {
    const int nr = r + i * 16;
    ushort4 o;
    o.x = f2bf(t[c4 * 4 + 0][nr]);
    o.y = f2bf(t[c4 * 4 + 1][nr]);
    o.z = f2bf(t[c4 * 4 + 2][nr]);
    o.w = f2bf(t[c4 * 4 + 3][nr]);
    *(ushort4*)(O + (size_t)(n0 + nr) * 1024 + k0 + c4 * 4) = o;
  }
}

// ---------------------------------------------------------------------------
// Kernel 2: triple GEMM, shared A.
// R7 post-mortem: XCD remap fixed bytes (FETCH 137->44 MB) but time unchanged
// -- 80 KB LDS forced 1 block/CU (occupancy 22%), so the per-K-step vmcnt(0)
// drain at the barrier had no co-resident block to hide it (every pipe <25%).
// R8 fix: SINGLE-BUFFER everything -> 40 KB LDS -> 3 blocks/CU (m97's proven
// operating point: cross-block overlap covers the drain, 874 TF regime).
// m97 schedule: writeX+stageB -> barrier -> loadX(next) || ds_read+MFMA ->
// barrier. Geometry/swizzle/epilogue/XCD-remap identical to R7:
// BM=256 BN=128 BK=32, 8 waves 2Mx4N (wave 128x32),
// swz(row)=((row>>1)&3)<<4 on gload_lds SOURCE + ds_write + ds_read.
//   ya  = relu(x@Wa + ba)      -> bf16 to ws
//   ysh = x@Wsh, ysc = x@Wsc   -> packed (bf16,bf16) u32 into d_out slots
// ---------------------------------------------------------------------------
__global__ __launch_bounds__(512, 4) void fused_gemm(
    const float* __restrict__ x,
    const unsigned short* __restrict__ Wta, const unsigned short* __restrict__ Wts,
    const unsigned short* __restrict__ Wtc,
    const float* __restrict__ ba,
    unsigned short* __restrict__ ya, unsigned int* __restrict__ pk)
{
  __shared__ unsigned short sX[256 * 32];   // 16 KB
  __shared__ unsigned short sA[128 * 32];   //  8 KB
  __shared__ unsigned short sS[128 * 32];   //  8 KB
  __shared__ unsigned short sC[128 * 32];   //  8 KB  -> 40 KB total

  const int tid = threadIdx.x;
  const int lane = tid & 63;
  const int wid = tid >> 6;      // 0..7
  const int wm = wid >> 2;       // 0..1 (M half: 128 rows)
  const int wn = wid & 3;        // 0..3 (N quarter: 32 cols)

  const int bid = blockIdx.x;        // 256 blocks = 32 M-tiles x 8 N-tiles
  const int xcd = bid & 7;           // XCD id under round-robin dispatch
  const int ntl = (bid >> 3) & 7;    // N tile (co-resident on this XCD)
  const int mg  = bid >> 6;          // M group 0..3
  const int bm0 = (xcd + (mg << 3)) * 256;   // each bm0 owned by ONE XCD
  const int bn0 = ntl * 128;

  // --- B staging map (gload_lds, wave-linear dest; swizzle via SOURCE) ---
  const int wrow  = wid * 16 + (lane >> 2);                        // 0..127
  const int gcolB = ((lane & 3) * 8) ^ (((wrow >> 1) & 3) * 8);    // bf16 units

  // --- X staging map (f32 -> bf16 -> swizzled ds_write) ---
  const int xr0 = tid >> 3;          // 0..63
  const int xcf = (tid & 7) * 4;     // f32 col
  const int xcb = xcf * 2;           // bf16 byte col (0..56)

  const int lr = lane & 15;          // frag col/row within 16
  const int lk = lane >> 4;          // 0..3: k-octet

  f32x4 accA[8][2], accS[8][2], accC[8][2];
  const f32x4 z = {0.f, 0.f, 0.f, 0.f};
#pragma unroll
  for (int m = 0; m < 8; ++m)
#pragma unroll
    for (int j = 0; j < 2; ++j) { accA[m][j] = z; accS[m][j] = z; accC[m][j] = z; }

  auto stageB = [&](int k0) {
    const size_t roff = (size_t)(bn0 + wrow) * 1024 + k0 + gcolB;
    const int doff = wid * 512;   // ushorts (1 KB per wave)
    __builtin_amdgcn_global_load_lds(
        (const __attribute__((address_space(1))) void*)(Wta + roff),
        (__attribute__((address_space(3))) void*)(sA + doff), 16, 0, 0);
    __builtin_amdgcn_global_load_lds(
        (const __attribute__((address_space(1))) void*)(Wts + roff),
        (__attribute__((address_space(3))) void*)(sS + doff), 16, 0, 0);
    __builtin_amdgcn_global_load_lds(
        (const __attribute__((address_space(1))) void*)(Wtc + roff),
        (__attribute__((address_space(3))) void*)(sC + doff), 16, 0, 0);
  };
  auto loadX = [&](int k0, float4* xv) {
#pragma unroll
    for (int i = 0; i < 4; ++i)
      xv[i] = *(const float4*)(x + (size_t)(bm0 + i * 64 + xr0) * 1024 + k0 + xcf);
  };
  auto writeX = [&](const float4* xv) {
#pragma unroll
    for (int i = 0; i < 4; ++i) {
      ushort4 o;
      o.x = f2bf(xv[i].x); o.y = f2bf(xv[i].y);
      o.z = f2bf(xv[i].z); o.w = f2bf(xv[i].w);
      const int row = i * 64 + xr0;
      const int po = row * 64 + (xcb ^ (((row >> 1) & 3) << 4));
      *(ushort4*)((char*)sX + po) = o;
    }
  };

  // prologue: x regs for tile 0
  float4 xv[4];
  loadX(0, xv);

  for (int kt = 0; kt < 32; ++kt) {
    // buffer is free here (barrier at end of previous iteration)
    writeX(xv);                 // ds_write current tile's X (vmcnt wait auto)
    stageB(kt * 32);            // gload_lds B tiles for this step
    __syncthreads();            // drain vmcnt+lgkm: LDS tile ready

    if (kt + 1 < 32)
      loadX((kt + 1) * 32, xv); // reg-prefetch next X under the MFMA phase

    // B fragments (6 reads), then 8 x {1 A read, 6 MFMAs}
    bf16x8 bA[2], bS[2], bC[2];
#pragma unroll
    for (int j = 0; j < 2; ++j) {
      const int row = wn * 32 + j * 16 + lr;
      const int po = row * 64 + ((lk * 16) ^ (((row >> 1) & 3) << 4));
      bA[j] = *(const bf16x8*)((const char*)sA + po);
      bS[j] = *(const bf16x8*)((const char*)sS + po);
      bC[j] = *(const bf16x8*)((const char*)sC + po);
    }
    __builtin_amdgcn_s_setprio(1);
#pragma unroll
    for (int m = 0; m < 8; ++m) {
      const int row = wm * 128 + m * 16 + lr;
      const int po = row * 64 + ((lk * 16) ^ (((row >> 1) & 3) << 4));
      const bf16x8 ax = *(const bf16x8*)((const char*)sX + po);
#pragma unroll
      for (int j = 0; j < 2; ++j) {
        accA[m][j] = __builtin_amdgcn_mfma_f32_16x16x32_bf16(ax, bA[j], accA[m][j], 0, 0, 0);
        accS[m][j] = __builtin_amdgcn_mfma_f32_16x16x32_bf16(ax, bS[j], accS[m][j], 0, 0, 0);
        accC[m][j] = __builtin_amdgcn_mfma_f32_16x16x32_bf16(ax, bC[j], accC[m][j], 0, 0, 0);
      }
    }
    __builtin_amdgcn_s_setprio(0);

    __syncthreads();            // all reads done; buffer reusable
  }

  // epilogue. C/D layout: col=lane&15, row=(lane>>4)*4+reg [measured m89/m91]
#pragma unroll
  for (int j = 0; j < 2; ++j) {
    const int n = bn0 + wn * 32 + j * 16 + lr;
    const float Ba = ba[n];
#pragma unroll
    for (int m = 0; m < 8; ++m) {
      const int rbase = bm0 + wm * 128 + m * 16 + lk * 4;
#pragma unroll
      for (int r = 0; r < 4; ++r) {
        const size_t idx = (size_t)(rbase + r) * 1024 + n;
        const float aff = fmaxf(accA[m][j][r] + Ba, 0.0f);
        ya[idx] = f2bf(aff);
        pk[idx] = (unsigned int)f2bf(accS[m][j][r]) |
                  ((unsigned int)f2bf(accC[m][j][r]) << 16);
      }
    }
  }
}

// ---------------------------------------------------------------------------
// Kernel 3: causal Gaussian filter along t + combine, IN PLACE over d_out.
//   shift = filter(ysh)+bsh; scale = filter(ysc)+bsc; out = scale*ya + shift
// Each block owns one (batch, 32-col slice); halo pre-read into regs before a
// barrier so f32 overwrites never race bf16 reads. Static indexing (rule #20).
// ---------------------------------------------------------------------------
__global__ __launch_bounds__(512) void filter_combine(
    void* slab,                         // d_out: read packed u32, write f32
    const unsigned short* __restrict__ ya,
    const float* __restrict__ bshift, const float* __restrict__ bscale)
{
  const unsigned int* pk = (const unsigned int*)slab;
  float* outf = (float*)slab;

  const int tid = threadIdx.x;
  const int b = blockIdx.x >> 5;            // 8 batches
  const int n0 = (blockIdx.x & 31) << 5;    // 32 col-slices
  const int lane = tid & 63;
  const int w = tid >> 6;                   // 0..7
  const int seg = (w << 1) | (lane >> 5);   // 0..15, 64 t-rows each
  const int col = lane & 31;
  const int n = n0 + col;
  const int t0 = seg * 64;
  const size_t base = (size_t)b * 1024 * 1024 + n;  // + t*1024

  float g[16];
#pragma unroll
  for (int k = 0; k < 16; ++k) g[k] = __expf(-(float)(k * k) * 0.125f);
  float nfull = 0.f;
#pragma unroll
  for (int k = 0; k < 16; ++k) nfull += g[k];
  const float invf = 1.0f / nfull;

  // halo pre-read: rows t0-15 .. t0-1 (zeros at batch start)
  float psh[15], psc[15];
#pragma unroll
  for (int i = 0; i < 15; ++i) {
    float vs = 0.f, vc = 0.f;
    if (t0 > 0) {
      const unsigned int u = pk[base + (size_t)(t0 - 15 + i) * 1024];
      vs = bf2f(u & 0xffffu); vc = bf2f(u >> 16);
    }
    psh[i] = vs; psc[i] = vc;
  }
  __syncthreads();   // all halo reads complete before any f32 overwrite

  const float bs = bshift[n];
  const float bc = bscale[n];

  for (int c = 0; c < 4; ++c) {             // 4 chunks of 16 t-rows
    const int T = t0 + c * 16;
    unsigned int cu[16];
#pragma unroll
    for (int u = 0; u < 16; ++u) cu[u] = pk[base + (size_t)(T + u) * 1024];
    unsigned short yv[16];
#pragma unroll
    for (int u = 0; u < 16; ++u) yv[u] = ya[base + (size_t)(T + u) * 1024];
    float csh[16], csc[16];
#pragma unroll
    for (int u = 0; u < 16; ++u) {
      csh[u] = bf2f(cu[u] & 0xffffu);
      csc[u] = bf2f(cu[u] >> 16);
    }
#pragma unroll
    for (int u = 0; u < 16; ++u) {
      float fs = 0.f, fc = 0.f;
#pragma unroll
      for (int k = 0; k < 16; ++k) {
        const int d = u - k;
        const float vs = (d >= 0) ? csh[d] : psh[15 + d];
        const float vc = (d >= 0) ? csc[d] : psc[15 + d];
        fs = fmaf(g[k], vs, fs);
        fc = fmaf(g[k], vc, fc);
      }
      const int t = T + u;
      float inv = invf;
      if (t < 15) {                          // batch start: partial norm
        float s = 0.f;
#pragma unroll
        for (int k = 0; k < 16; ++k) s += (k <= t) ? g[k] : 0.f;
        inv = 1.0f / s;
      }
      const float shiftv = fs * inv + bs;
      const float scalev = fc * inv + bc;
      const float aff = bf2f((unsigned int)yv[u]);
      outf[base + (size_t)t * 1024] = scalev * aff + shiftv;
    }
#pragma unroll
    for (int i = 0; i < 15; ++i) { psh[i] = csh[i + 1]; psc[i] = csc[i + 1]; }
  }
}

// ---------------------------------------------------------------------------
// Workspace layout (22 MiB, proven safe; ws_size known to be in [22,38) MiB):
//   ya  : ws + 0        16 MiB (affine, bf16)
//   Wta : ws + 16 MiB    2 MiB (Wa^T bf16)
//   Wts : ws + 18 MiB    2 MiB (Wshift^T bf16)
//   Wtc : ws + 20 MiB    2 MiB (Wscale^T bf16)
// d_out doubles as the (ysh,ysc) bf16-pair slab before filter_combine
// overwrites it in place with the final f32 output.
// ---------------------------------------------------------------------------
extern "C" void kernel_launch(void* const* d_in, const int* in_sizes, int n_in,
                              void* d_out, int out_size, void* d_ws, size_t ws_size,
                              hipStream_t stream) {
  const float* x   = (const float*)d_in[0];
  const float* Wa  = (const float*)d_in[1];
  const float* ba  = (const float*)d_in[2];
  const float* Wsh = (const float*)d_in[3];
  const float* bsh = (const float*)d_in[4];
  const float* Wsc = (const float*)d_in[5];
  const float* bsc = (const float*)d_in[6];

  char* ws = (char*)d_ws;
  unsigned short* ya  = (unsigned short*)(ws);
  unsigned short* Wta = (unsigned short*)(ws + (16u << 20));
  unsigned short* Wts = (unsigned short*)(ws + (18u << 20));
  unsigned short* Wtc = (unsigned short*)(ws + (20u << 20));

  hipLaunchKernelGGL(wconv, dim3(16, 16, 3), dim3(256), 0, stream,
                     Wa, Wsh, Wsc, Wta, Wts, Wtc);
  hipLaunchKernelGGL(fused_gemm, dim3(256), dim3(512), 0, stream,
                     x, Wta, Wts, Wtc, ba, ya, (unsigned int*)d_out);
  hipLaunchKernelGGL(filter_combine, dim3(256), dim3(512), 0, stream,
                     d_out, ya, bsh, bsc);
}

// Round 9
// 140.309 us; speedup vs baseline: 4.7567x; 4.7567x over previous
//
#include <hip/hip_runtime.h>
#include <stdint.h>

typedef __attribute__((ext_vector_type(8))) __bf16 bf16x8;
typedef __attribute__((ext_vector_type(4))) float f32x4;

__device__ __forceinline__ unsigned short f2bf(float f) {
  union { float f; unsigned int u; } v; v.f = f;
  unsigned int u = v.u;
  u = (u + 0x7FFFu + ((u >> 16) & 1u)) >> 16;   // RNE
  return (unsigned short)u;
}
__device__ __forceinline__ float bf2f(unsigned int u) {
  union { unsigned int u; float f; } v; v.u = u << 16;
  return v.f;
}

// ---------------------------------------------------------------------------
// Kernel 1: transpose + bf16-convert the three DxD weight matrices into one
// concatenated B' (3072 x 1024): Wt3[mat*1024 + n][k] = (bf16) W_mat[k][n].
// ---------------------------------------------------------------------------
__global__ __launch_bounds__(256) void wconv(
    const float* __restrict__ Wa, const float* __restrict__ Wsh,
    const float* __restrict__ Wsc, unsigned short* __restrict__ Wt3)
{
  const float* W;
  if (blockIdx.z == 0)      W = Wa;
  else if (blockIdx.z == 1) W = Wsh;
  else                      W = Wsc;
  unsigned short* O = Wt3 + (size_t)blockIdx.z * 1024 * 1024;
  const int k0 = blockIdx.x * 64;
  const int n0 = blockIdx.y * 64;
  __shared__ float t[64][65];
  const int r = threadIdx.x >> 4;
  const int c4 = threadIdx.x & 15;
#pragma unroll
  for (int i = 0; i < 4; ++i) {
    const int row = r + i * 16;
    const float4 v = *(const float4*)(W + (size_t)(k0 + row) * 1024 + n0 + c4 * 4);
    t[row][c4 * 4 + 0] = v.x; t[row][c4 * 4 + 1] = v.y;
    t[row][c4 * 4 + 2] = v.z; t[row][c4 * 4 + 3] = v.w;
  }
  __syncthreads();
#pragma unroll
  for (int i = 0; i < 4; ++i) {
    const int nr = r + i * 16;
    ushort4 o;
    o.x = f2bf(t[c4 * 4 + 0][nr]);
    o.y = f2bf(t[c4 * 4 + 1][nr]);
    o.z = f2bf(t[c4 * 4 + 2][nr]);
    o.w = f2bf(t[c4 * 4 + 3][nr]);
    *(ushort4*)(O + (size_t)(n0 + nr) * 1024 + k0 + c4 * 4) = o;
  }
}

// ---------------------------------------------------------------------------
// Kernel 2: ONE standard GEMM  C'[8192 x 3072] = x[8192 x 1024] @ B'^T,
// B' = concat(Wa^T | Wsh^T | Wsc^T).
// R8 post-mortem: all prior rounds ran ONE 8-wave barrier-synced block/CU
// (224 unified regs/wave -> 2 waves/SIMD), so every per-K-step vmcnt(0)
// drain idled the whole CU. m97's 874 TF uses 4-wave blocks with 2-3
// INDEPENDENT blocks/CU covering each other's drains (m114).
// R9: m97-faithful config. BM=BN=128, BK=64, 4 waves (256 thr), wave tile
// 64x64 -> ONE acc set = 64 regs (vs 192 for the 3-acc fused version).
// Single-buffer 32 KB LDS, 2-barrier loop, reg-staged X (f32->bf16) +
// gload_lds B with pre-swizzled source; swz(row)=(row&7)<<4 both sides.
// Epilogue by n'>>10: mat0 -> ya=relu(+ba) bf16; mat1/2 -> u16 halves of pk.
// ---------------------------------------------------------------------------
__global__ __launch_bounds__(256, 2) void gemm3(
    const float* __restrict__ x, const unsigned short* __restrict__ Wt3,
    const float* __restrict__ ba,
    unsigned short* __restrict__ ya, unsigned short* __restrict__ pk16)
{
  __shared__ unsigned short sX[128 * 64];   // 16 KB
  __shared__ unsigned short sB[128 * 64];   // 16 KB

  const int tid = threadIdx.x;
  const int lane = tid & 63;
  const int wid = tid >> 6;      // 0..3
  const int wm = wid >> 1;       // 0..1
  const int wn = wid & 1;        // 0..1

  // 1536 blocks = 64 M-tiles x 24 N-tiles. XCD-ownership remap (R7, proven):
  // xcd = bid&7 owns M-slices {xcd, xcd+8, ..}; its 24 N-consumers + all its
  // M-groups are co-resident on that XCD -> x HBM-fetched once, L2 re-read.
  const int bid = blockIdx.x;
  const int xcd = bid & 7;
  const int r   = bid >> 3;          // 0..191
  const int ntl = r % 24;            // N tile
  const int mg  = r / 24;            // M group 0..7
  const int bm0 = (xcd + (mg << 3)) * 128;
  const int bn0 = ntl * 128;

  // --- B staging map (gload_lds; swizzle via pre-swizzled SOURCE, rule #21)
  int rowS[4], colS[4];
#pragma unroll
  for (int p = 0; p < 4; ++p) {
    const int po = (p * 256 + tid) * 16;      // phys byte in 16 KB tile
    const int rr = po >> 7;                   // 128 B per row (64 bf16)
    const int lo = po ^ ((rr & 7) << 4);
    rowS[p] = rr;
    colS[p] = (lo & 127) >> 1;                // bf16 col
  }

  // --- X staging map: 8 rounds x 16 rows; 16 thr cover one 256 B f32 row ---
  const int xr0 = tid >> 4;          // 0..15
  const int xcf = (tid & 15) * 4;    // f32 col 0..60
  const int xcb = xcf * 2;           // bf16 byte col
  const int lr = lane & 15;
  const int lk = lane >> 4;

  f32x4 acc[4][4];                   // 64 regs, one output matrix tile
  const f32x4 z = {0.f, 0.f, 0.f, 0.f};
#pragma unroll
  for (int m = 0; m < 4; ++m)
#pragma unroll
    for (int j = 0; j < 4; ++j) acc[m][j] = z;

  auto stageB = [&](int k0) {
#pragma unroll
    for (int p = 0; p < 4; ++p) {
      const unsigned short* src =
          Wt3 + (size_t)(bn0 + rowS[p]) * 1024 + k0 + colS[p];
      __builtin_amdgcn_global_load_lds(
          (const __attribute__((address_space(1))) void*)src,
          (__attribute__((address_space(3))) void*)(sB + (p * 256 + (wid << 6)) * 8),
          16, 0, 0);
    }
  };
  auto loadX = [&](int k0, float4* xv) {
#pragma unroll
    for (int i = 0; i < 8; ++i)
      xv[i] = *(const float4*)(x + (size_t)(bm0 + i * 16 + xr0) * 1024 + k0 + xcf);
  };
  auto writeX = [&](const float4* xv) {
#pragma unroll
    for (int i = 0; i < 8; ++i) {
      ushort4 o;
      o.x = f2bf(xv[i].x); o.y = f2bf(xv[i].y);
      o.z = f2bf(xv[i].z); o.w = f2bf(xv[i].w);
      const int row = i * 16 + xr0;
      const int po = row * 128 + (xcb ^ ((row & 7) << 4));
      *(ushort4*)((char*)sX + po) = o;
    }
  };

  float4 xv[8];
  loadX(0, xv);

  for (int kt = 0; kt < 16; ++kt) {
    // previous iteration's trailing barrier guarantees sX/sB are free
    writeX(xv);                 // compiler waits xv's vmcnt, then ds_write
    stageB(kt * 64);
    __syncthreads();            // tile ready (vmcnt+lgkm drained)

    if (kt + 1 < 16)
      loadX((kt + 1) * 64, xv); // reg-prefetch next X under MFMA phase

#pragma unroll
    for (int s = 0; s < 2; ++s) {
      bf16x8 ax[4], bb[4];
#pragma unroll
      for (int m = 0; m < 4; ++m) {
        const int row = wm * 64 + m * 16 + lr;
        const int po = row * 128 + (((s * 32 + lk * 8) * 2) ^ ((row & 7) << 4));
        ax[m] = *(const bf16x8*)((const char*)sX + po);
      }
#pragma unroll
      for (int j = 0; j < 4; ++j) {
        const int row = wn * 64 + j * 16 + lr;
        const int po = row * 128 + (((s * 32 + lk * 8) * 2) ^ ((row & 7) << 4));
        bb[j] = *(const bf16x8*)((const char*)sB + po);
      }
      __builtin_amdgcn_s_setprio(1);
#pragma unroll
      for (int m = 0; m < 4; ++m)
#pragma unroll
        for (int j = 0; j < 4; ++j)
          acc[m][j] = __builtin_amdgcn_mfma_f32_16x16x32_bf16(ax[m], bb[j], acc[m][j], 0, 0, 0);
      __builtin_amdgcn_s_setprio(0);
    }
    __syncthreads();            // all reads done; buffers reusable
  }

  // epilogue. C/D layout: col=lane&15, row=(lane>>4)*4+reg [m89/m91].
  // mat = n'>>10 is uniform per (wave, j): 16-col chunks never straddle 1024.
#pragma unroll
  for (int j = 0; j < 4; ++j) {
    const int np = bn0 + wn * 64 + j * 16 + lr;
    const int mat = np >> 10;
    const int nn = np & 1023;
    const float Ba = (mat == 0) ? ba[nn] : 0.0f;
#pragma unroll
    for (int m = 0; m < 4; ++m) {
      const int rbase = bm0 + wm * 64 + m * 16 + lk * 4;
#pragma unroll
      for (int q = 0; q < 4; ++q) {
        const size_t idx = (size_t)(rbase + q) * 1024 + nn;
        const float v = acc[m][j][q];
        if (mat == 0) {
          ya[idx] = f2bf(fmaxf(v + Ba, 0.0f));
        } else if (mat == 1) {
          pk16[idx * 2] = f2bf(v);          // ysh -> low u16
        } else {
          pk16[idx * 2 + 1] = f2bf(v);      // ysc -> high u16
        }
      }
    }
  }
}

// ---------------------------------------------------------------------------
// Kernel 3: causal Gaussian filter along t + combine, IN PLACE over d_out.
//   shift = filter(ysh)+bsh; scale = filter(ysc)+bsc; out = scale*ya + shift
// Each block owns one (batch, 32-col slice); halo pre-read into regs before a
// barrier so f32 overwrites never race bf16 reads. Static indexing (rule #20).
// ---------------------------------------------------------------------------
__global__ __launch_bounds__(512) void filter_combine(
    void* slab,                         // d_out: read packed u32, write f32
    const unsigned short* __restrict__ ya,
    const float* __restrict__ bshift, const float* __restrict__ bscale)
{
  const unsigned int* pk = (const unsigned int*)slab;
  float* outf = (float*)slab;

  const int tid = threadIdx.x;
  const int b = blockIdx.x >> 5;            // 8 batches
  const int n0 = (blockIdx.x & 31) << 5;    // 32 col-slices
  const int lane = tid & 63;
  const int w = tid >> 6;                   // 0..7
  const int seg = (w << 1) | (lane >> 5);   // 0..15, 64 t-rows each
  const int col = lane & 31;
  const int n = n0 + col;
  const int t0 = seg * 64;
  const size_t base = (size_t)b * 1024 * 1024 + n;  // + t*1024

  float g[16];
#pragma unroll
  for (int k = 0; k < 16; ++k) g[k] = __expf(-(float)(k * k) * 0.125f);
  float nfull = 0.f;
#pragma unroll
  for (int k = 0; k < 16; ++k) nfull += g[k];
  const float invf = 1.0f / nfull;

  // halo pre-read: rows t0-15 .. t0-1 (zeros at batch start)
  float psh[15], psc[15];
#pragma unroll
  for (int i = 0; i < 15; ++i) {
    float vs = 0.f, vc = 0.f;
    if (t0 > 0) {
      const unsigned int u = pk[base + (size_t)(t0 - 15 + i) * 1024];
      vs = bf2f(u & 0xffffu); vc = bf2f(u >> 16);
    }
    psh[i] = vs; psc[i] = vc;
  }
  __syncthreads();   // all halo reads complete before any f32 overwrite

  const float bs = bshift[n];
  const float bc = bscale[n];

  for (int c = 0; c < 4; ++c) {             // 4 chunks of 16 t-rows
    const int T = t0 + c * 16;
    unsigned int cu[16];
#pragma unroll
    for (int u = 0; u < 16; ++u) cu[u] = pk[base + (size_t)(T + u) * 1024];
    unsigned short yv[16];
#pragma unroll
    for (int u = 0; u < 16; ++u) yv[u] = ya[base + (size_t)(T + u) * 1024];
    float csh[16], csc[16];
#pragma unroll
    for (int u = 0; u < 16; ++u) {
      csh[u] = bf2f(cu[u] & 0xffffu);
      csc[u] = bf2f(cu[u] >> 16);
    }
#pragma unroll
    for (int u = 0; u < 16; ++u) {
      float fs = 0.f, fc = 0.f;
#pragma unroll
      for (int k = 0; k < 16; ++k) {
        const int d = u - k;
        const float vs = (d >= 0) ? csh[d] : psh[15 + d];
        const float vc = (d >= 0) ? csc[d] : psc[15 + d];
        fs = fmaf(g[k], vs, fs);
        fc = fmaf(g[k], vc, fc);
      }
      const int t = T + u;
      float inv = invf;
      if (t < 15) {                          // batch start: partial norm
        float s = 0.f;
#pragma unroll
        for (int k = 0; k < 16; ++k) s += (k <= t) ? g[k] : 0.f;
        inv = 1.0f / s;
      }
      const float shiftv = fs * inv + bs;
      const float scalev = fc * inv + bc;
      const float aff = bf2f((unsigned int)yv[u]);
      outf[base + (size_t)t * 1024] = scalev * aff + shiftv;
    }
#pragma unroll
    for (int i = 0; i < 15; ++i) { psh[i] = csh[i + 1]; psc[i] = csc[i + 1]; }
  }
}

// ---------------------------------------------------------------------------
// Workspace layout (22 MiB, proven safe; ws_size known to be in [22,38) MiB):
//   ya  : ws + 0        16 MiB (affine, bf16)
//   Wt3 : ws + 16 MiB    6 MiB (concat Wa^T|Wshift^T|Wscale^T, bf16)
// d_out doubles as the (ysh,ysc) bf16-pair slab before filter_combine
// overwrites it in place with the final f32 output.
// ---------------------------------------------------------------------------
extern "C" void kernel_launch(void* const* d_in, const int* in_sizes, int n_in,
                              void* d_out, int out_size, void* d_ws, size_t ws_size,
                              hipStream_t stream) {
  const float* x   = (const float*)d_in[0];
  const float* Wa  = (const float*)d_in[1];
  const float* ba  = (const float*)d_in[2];
  const float* Wsh = (const float*)d_in[3];
  const float* bsh = (const float*)d_in[4];
  const float* Wsc = (const float*)d_in[5];
  const float* bsc = (const float*)d_in[6];

  char* ws = (char*)d_ws;
  unsigned short* ya  = (unsigned short*)(ws);
  unsigned short* Wt3 = (unsigned short*)(ws + (16u << 20));

  hipLaunchKernelGGL(wconv, dim3(16, 16, 3), dim3(256), 0, stream,
                     Wa, Wsh, Wsc, Wt3);
  hipLaunchKernelGGL(gemm3, dim3(1536), dim3(256), 0, stream,
                     x, Wt3, ba, ya, (unsigned short*)d_out);
  hipLaunchKernelGGL(filter_combine, dim3(256), dim3(512), 0, stream,
                     d_out, ya, bsh, bsc);
}

// Round 10
// 139.536 us; speedup vs baseline: 4.7830x; 1.0055x over previous
//
#include <hip/hip_runtime.h>
#include <stdint.h>

typedef __attribute__((ext_vector_type(8))) __bf16 bf16x8;
typedef __attribute__((ext_vector_type(4))) float f32x4;

__device__ __forceinline__ unsigned short f2bf(float f) {
  union { float f; unsigned int u; } v; v.f = f;
  unsigned int u = v.u;
  u = (u + 0x7FFFu + ((u >> 16) & 1u)) >> 16;   // RNE
  return (unsigned short)u;
}
__device__ __forceinline__ float bf2f(unsigned int u) {
  union { unsigned int u; float f; } v; v.u = u << 16;
  return v.f;
}

// ---------------------------------------------------------------------------
// Kernel 1: transpose + bf16-convert the three DxD weight matrices into one
// concatenated B' (3072 x 1024): Wt3[mat*1024 + n][k] = (bf16) W_mat[k][n].
// ---------------------------------------------------------------------------
__global__ __launch_bounds__(256) void wconv(
    const float* __restrict__ Wa, const float* __restrict__ Wsh,
    const float* __restrict__ Wsc, unsigned short* __restrict__ Wt3)
{
  const float* W;
  if (blockIdx.z == 0)      W = Wa;
  else if (blockIdx.z == 1) W = Wsh;
  else                      W = Wsc;
  unsigned short* O = Wt3 + (size_t)blockIdx.z * 1024 * 1024;
  const int k0 = blockIdx.x * 64;
  const int n0 = blockIdx.y * 64;
  __shared__ float t[64][65];
  const int r = threadIdx.x >> 4;
  const int c4 = threadIdx.x & 15;
#pragma unroll
  for (int i = 0; i < 4; ++i) {
    const int row = r + i * 16;
    const float4 v = *(const float4*)(W + (size_t)(k0 + row) * 1024 + n0 + c4 * 4);
    t[row][c4 * 4 + 0] = v.x; t[row][c4 * 4 + 1] = v.y;
    t[row][c4 * 4 + 2] = v.z; t[row][c4 * 4 + 3] = v.w;
  }
  __syncthreads();
#pragma unroll
  for (int i = 0; i < 4; ++i) {
    const int nr = r + i * 16;
    ushort4 o;
    o.x = f2bf(t[c4 * 4 + 0][nr]);
    o.y = f2bf(t[c4 * 4 + 1][nr]);
    o.z = f2bf(t[c4 * 4 + 2][nr]);
    o.w = f2bf(t[c4 * 4 + 3][nr]);
    *(ushort4*)(O + (size_t)(n0 + nr) * 1024 + k0 + c4 * 4) = o;
  }
}

// ---------------------------------------------------------------------------
// Kernel 2: ONE GEMM  C'[8192 x 3072] = x @ concat(Wa^T|Wsh^T|Wsc^T)^T.
// R9 post-mortem: every prior variant drained vmcnt(0)+lgkm at EVERY K-step
// barrier (__syncthreads semantics) -> prefetches never survive a barrier;
// with <=8 waves/CU the ~900cyc load+drain serializes vs ~160cyc MFMA. That
// drain is the invariant across the 100-125us plateau (m233/m218).
// R10: T4 counted-vmcnt protocol, geometry/maps/epilogue identical to R9.
// Depth-2 LDS ring (2x32KB = 64KB -> still 2 blocks/CU), raw s_barrier,
// vmcnt(12) (= the 12 in-flight next-tile ops) instead of drain-0; loads for
// tile t+1 stay in flight across BOTH barriers of iter t. Fully unrolled
// K-loop -> static slot indices + literal vmcnt immediates (rule #20).
// Race check (m152): stage(t+1) writes slot (t+1)&1, whose readers finished
// before iter t-1's trailing barrier, which precedes the issue. writeX(t)
// targets slot t&1, last read before iter t-2's trailing barrier.
// ---------------------------------------------------------------------------
__global__ __launch_bounds__(256, 2) void gemm3(
    const float* __restrict__ x, const unsigned short* __restrict__ Wt3,
    const float* __restrict__ ba,
    unsigned short* __restrict__ ya, unsigned short* __restrict__ pk16)
{
  __shared__ unsigned short sX[2][128 * 64];   // 2 x 16 KB
  __shared__ unsigned short sB[2][128 * 64];   // 2 x 16 KB

  const int tid = threadIdx.x;
  const int lane = tid & 63;
  const int wid = tid >> 6;      // 0..3
  const int wm = wid >> 1;       // 0..1
  const int wn = wid & 1;        // 0..1

  // 1536 blocks = 64 M-tiles x 24 N-tiles. XCD-ownership remap (R7-proven).
  const int bid = blockIdx.x;
  const int xcd = bid & 7;
  const int r   = bid >> 3;          // 0..191
  const int ntl = r % 24;            // N tile (fast within XCD: B panel hot)
  const int mg  = r / 24;            // M group 0..7
  const int bm0 = (xcd + (mg << 3)) * 128;
  const int bn0 = ntl * 128;

  // --- B staging map (gload_lds; swizzle via pre-swizzled SOURCE, rule #21)
  int rowS[4], colS[4];
#pragma unroll
  for (int p = 0; p < 4; ++p) {
    const int po = (p * 256 + tid) * 16;      // phys byte in 16 KB tile
    const int rr = po >> 7;                   // 128 B per row (64 bf16)
    const int lo = po ^ ((rr & 7) << 4);
    rowS[p] = rr;
    colS[p] = (lo & 127) >> 1;                // bf16 col
  }

  // --- X staging map: 8 rounds x 16 rows; 16 thr cover one 256 B f32 row ---
  const int xr0 = tid >> 4;          // 0..15
  const int xcf = (tid & 15) * 4;    // f32 col 0..60
  const int xcb = xcf * 2;           // bf16 byte col
  const int lr = lane & 15;
  const int lk = lane >> 4;

  f32x4 acc[4][4];                   // 64 regs, one output matrix tile
  const f32x4 z = {0.f, 0.f, 0.f, 0.f};
#pragma unroll
  for (int m = 0; m < 4; ++m)
#pragma unroll
    for (int j = 0; j < 4; ++j) acc[m][j] = z;

  auto stageB = [&](int k0, int buf) {
#pragma unroll
    for (int p = 0; p < 4; ++p) {
      const unsigned short* src =
          Wt3 + (size_t)(bn0 + rowS[p]) * 1024 + k0 + colS[p];
      __builtin_amdgcn_global_load_lds(
          (const __attribute__((address_space(1))) void*)src,
          (__attribute__((address_space(3))) void*)(&sB[buf][0] + (p * 256 + (wid << 6)) * 8),
          16, 0, 0);
    }
  };
  auto loadX = [&](int k0, float4* xv) {
#pragma unroll
    for (int i = 0; i < 8; ++i)
      xv[i] = *(const float4*)(x + (size_t)(bm0 + i * 16 + xr0) * 1024 + k0 + xcf);
  };
  auto writeX = [&](int buf, const float4* xv) {
#pragma unroll
    for (int i = 0; i < 8; ++i) {
      ushort4 o;
      o.x = f2bf(xv[i].x); o.y = f2bf(xv[i].y);
      o.z = f2bf(xv[i].z); o.w = f2bf(xv[i].w);
      const int row = i * 16 + xr0;
      const int po = row * 128 + (xcb ^ ((row & 7) << 4));
      *(ushort4*)((char*)&sX[buf][0] + po) = o;
    }
  };

  float4 xv[8];
  loadX(0, xv);          // tile 0 X -> regs
  stageB(0, 0);          // tile 0 B -> LDS (in flight)

#pragma unroll
  for (int kt = 0; kt < 16; ++kt) {
    const int cur = kt & 1;

    // consume xv(kt) (compiler inserts the minimal vmcnt wait for xv only)
    writeX(cur, xv);
    // issue tile kt+1: these 12 VMEM ops stay in flight across both barriers
    if (kt + 1 < 16) {
      loadX((kt + 1) * 64, xv);
      stageB((kt + 1) * 64, cur ^ 1);
    }

    // T4: counted vmcnt -- tile kt's stageB complete; 12 newer ops remain.
    if (kt + 1 < 16) {
      asm volatile("s_waitcnt vmcnt(12)" ::: "memory");
    } else {
      asm volatile("s_waitcnt vmcnt(0)" ::: "memory");
    }
    asm volatile("s_waitcnt lgkmcnt(0)" ::: "memory");   // writeX visible
    __builtin_amdgcn_sched_barrier(0);
    __builtin_amdgcn_s_barrier();                        // tile kt ready
    __builtin_amdgcn_sched_barrier(0);

#pragma unroll
    for (int s = 0; s < 2; ++s) {
      bf16x8 ax[4], bb[4];
#pragma unroll
      for (int m = 0; m < 4; ++m) {
        const int row = wm * 64 + m * 16 + lr;
        const int po = row * 128 + (((s * 32 + lk * 8) * 2) ^ ((row & 7) << 4));
        ax[m] = *(const bf16x8*)((const char*)&sX[cur][0] + po);
      }
#pragma unroll
      for (int j = 0; j < 4; ++j) {
        const int row = wn * 64 + j * 16 + lr;
        const int po = row * 128 + (((s * 32 + lk * 8) * 2) ^ ((row & 7) << 4));
        bb[j] = *(const bf16x8*)((const char*)&sB[cur][0] + po);
      }
      __builtin_amdgcn_s_setprio(1);
#pragma unroll
      for (int m = 0; m < 4; ++m)
#pragma unroll
        for (int j = 0; j < 4; ++j)
          acc[m][j] = __builtin_amdgcn_mfma_f32_16x16x32_bf16(ax[m], bb[j], acc[m][j], 0, 0, 0);
      __builtin_amdgcn_s_setprio(0);
    }

    __builtin_amdgcn_sched_barrier(0);
    asm volatile("s_waitcnt lgkmcnt(0)" ::: "memory");   // all slot reads done
    __builtin_amdgcn_s_barrier();                        // slot reusable
    __builtin_amdgcn_sched_barrier(0);
  }

  // epilogue. C/D layout: col=lane&15, row=(lane>>4)*4+reg [m89/m91].
  // mat = n'>>10 is uniform per (wave, j): 16-col chunks never straddle 1024.
#pragma unroll
  for (int j = 0; j < 4; ++j) {
    const int np = bn0 + wn * 64 + j * 16 + lr;
    const int mat = np >> 10;
    const int nn = np & 1023;
    const float Ba = (mat == 0) ? ba[nn] : 0.0f;
#pragma unroll
    for (int m = 0; m < 4; ++m) {
      const int rbase = bm0 + wm * 64 + m * 16 + lk * 4;
#pragma unroll
      for (int q = 0; q < 4; ++q) {
        const size_t idx = (size_t)(rbase + q) * 1024 + nn;
        const float v = acc[m][j][q];
        if (mat == 0) {
          ya[idx] = f2bf(fmaxf(v + Ba, 0.0f));
        } else if (mat == 1) {
          pk16[idx * 2] = f2bf(v);          // ysh -> low u16
        } else {
          pk16[idx * 2 + 1] = f2bf(v);      // ysc -> high u16
        }
      }
    }
  }
}

// ---------------------------------------------------------------------------
// Kernel 3: causal Gaussian filter along t + combine, IN PLACE over d_out.
//   shift = filter(ysh)+bsh; scale = filter(ysc)+bsc; out = scale*ya + shift
// Each block owns one (batch, 32-col slice); halo pre-read into regs before a
// barrier so f32 overwrites never race bf16 reads. Static indexing (rule #20).
// ---------------------------------------------------------------------------
__global__ __launch_bounds__(512) void filter_combine(
    void* slab,                         // d_out: read packed u32, write f32
    const unsigned short* __restrict__ ya,
    const float* __restrict__ bshift, const float* __restrict__ bscale)
{
  const unsigned int* pk = (const unsigned int*)slab;
  float* outf = (float*)slab;

  const int tid = threadIdx.x;
  const int b = blockIdx.x >> 5;            // 8 batches
  const int n0 = (blockIdx.x & 31) << 5;    // 32 col-slices
  const int lane = tid & 63;
  const int w = tid >> 6;                   // 0..7
  const int seg = (w << 1) | (lane >> 5);   // 0..15, 64 t-rows each
  const int col = lane & 31;
  const int n = n0 + col;
  const int t0 = seg * 64;
  const size_t base = (size_t)b * 1024 * 1024 + n;  // + t*1024

  float g[16];
#pragma unroll
  for (int k = 0; k < 16; ++k) g[k] = __expf(-(float)(k * k) * 0.125f);
  float nfull = 0.f;
#pragma unroll
  for (int k = 0; k < 16; ++k) nfull += g[k];
  const float invf = 1.0f / nfull;

  // halo pre-read: rows t0-15 .. t0-1 (zeros at batch start)
  float psh[15], psc[15];
#pragma unroll
  for (int i = 0; i < 15; ++i) {
    float vs = 0.f, vc = 0.f;
    if (t0 > 0) {
      const unsigned int u = pk[base + (size_t)(t0 - 15 + i) * 1024];
      vs = bf2f(u & 0xffffu); vc = bf2f(u >> 16);
    }
    psh[i] = vs; psc[i] = vc;
  }
  __syncthreads();   // all halo reads complete before any f32 overwrite

  const float bs = bshift[n];
  const float bc = bscale[n];

  for (int c = 0; c < 4; ++c) {             // 4 chunks of 16 t-rows
    const int T = t0 + c * 16;
    unsigned int cu[16];
#pragma unroll
    for (int u = 0; u < 16; ++u) cu[u] = pk[base + (size_t)(T + u) * 1024];
    unsigned short yv[16];
#pragma unroll
    for (int u = 0; u < 16; ++u) yv[u] = ya[base + (size_t)(T + u) * 1024];
    float csh[16], csc[16];
#pragma unroll
    for (int u = 0; u < 16; ++u) {
      csh[u] = bf2f(cu[u] & 0xffffu);
      csc[u] = bf2f(cu[u] >> 16);
    }
#pragma unroll
    for (int u = 0; u < 16; ++u) {
      float fs = 0.f, fc = 0.f;
#pragma unroll
      for (int k = 0; k < 16; ++k) {
        const int d = u - k;
        const float vs = (d >= 0) ? csh[d] : psh[15 + d];
        const float vc = (d >= 0) ? csc[d] : psc[15 + d];
        fs = fmaf(g[k], vs, fs);
        fc = fmaf(g[k], vc, fc);
      }
      const int t = T + u;
      float inv = invf;
      if (t < 15) {                          // batch start: partial norm
        float s = 0.f;
#pragma unroll
        for (int k = 0; k < 16; ++k) s += (k <= t) ? g[k] : 0.f;
        inv = 1.0f / s;
      }
      const float shiftv = fs * inv + bs;
      const float scalev = fc * inv + bc;
      const float aff = bf2f((unsigned int)yv[u]);
      outf[base + (size_t)t * 1024] = scalev * aff + shiftv;
    }
#pragma unroll
    for (int i = 0; i < 15; ++i) { psh[i] = csh[i + 1]; psc[i] = csc[i + 1]; }
  }
}

// ---------------------------------------------------------------------------
// Workspace layout (22 MiB, proven safe; ws_size known to be in [22,38) MiB):
//   ya  : ws + 0        16 MiB (affine, bf16)
//   Wt3 : ws + 16 MiB    6 MiB (concat Wa^T|Wshift^T|Wscale^T, bf16)
// d_out doubles as the (ysh,ysc) bf16-pair slab before filter_combine
// overwrites it in place with the final f32 output.
// ---------------------------------------------------------------------------
extern "C" void kernel_launch(void* const* d_in, const int* in_sizes, int n_in,
                              void* d_out, int out_size, void* d_ws, size_t ws_size,
                              hipStream_t stream) {
  const float* x   = (const float*)d_in[0];
  const float* Wa  = (const float*)d_in[1];
  const float* ba  = (const float*)d_in[2];
  const float* Wsh = (const float*)d_in[3];
  const float* bsh = (const float*)d_in[4];
  const float* Wsc = (const float*)d_in[5];
  const float* bsc = (const float*)d_in[6];

  char* ws = (char*)d_ws;
  unsigned short* ya  = (unsigned short*)(ws);
  unsigned short* Wt3 = (unsigned short*)(ws + (16u << 20));

  hipLaunchKernelGGL(wconv, dim3(16, 16, 3), dim3(256), 0, stream,
                     Wa, Wsh, Wsc, Wt3);
  hipLaunchKernelGGL(gemm3, dim3(1536), dim3(256), 0, stream,
                     x, Wt3, ba, ya, (unsigned short*)d_out);
  hipLaunchKernelGGL(filter_combine, dim3(256), dim3(512), 0, stream,
                     d_out, ya, bsh, bsc);
}